// Round 1
// baseline (14638.045 us; speedup 1.0000x reference)
//
#include <hip/hip_runtime.h>
#include <math.h>

#define NT 512        // time steps
#define NB 512        // batch
#define HID 128
#define NIN 10
#define NC 10         // memory cells
#define CW 20         // cell width
#define NIF 88        // interface size
#define NOUT 10
#define GB 2          // batches per workgroup
#define BLK 512       // threads per block (8 waves)

__device__ __forceinline__ float sigf(float x) { return 1.0f / (1.0f + expf(-x)); }
// jax.nn.softplus == logaddexp(x, 0)
__device__ __forceinline__ float splus(float x) { return fmaxf(x, 0.0f) + log1pf(expf(-fabsf(x))); }

__global__ __launch_bounds__(BLK) void dnc_fp32_kernel(
    const float* __restrict__ x,
    const float* __restrict__ Wih0, const float* __restrict__ Whh0, const float* __restrict__ b0,
    const float* __restrict__ Wih1, const float* __restrict__ Whh1, const float* __restrict__ b1,
    const float* __restrict__ Wif,  const float* __restrict__ bif,
    const float* __restrict__ Wout, const float* __restrict__ bout,
    float* __restrict__ out)
{
  __shared__ __align__(16) float s_inp[GB][32];
  __shared__ __align__(16) float s_h0[GB][HID], s_c0[GB][HID];
  __shared__ __align__(16) float s_h1[GB][HID], s_c1[GB][HID];
  __shared__ __align__(16) float s_ctrl[GB][HID];
  __shared__ __align__(16) float s_g[GB][4*HID];
  __shared__ float s_rk[GB][CW], s_wk[GB][CW], s_er[GB][CW], s_wv[GB][CW];
  __shared__ float s_mraw[GB][3];
  __shared__ float s_sc[GB][8];     // 0:rs 1:ws 2:fg 3:ga 4:gw 5:m0 6:m1 7:m2
  __shared__ float s_mem[GB][NC][CW];
  __shared__ float s_usage[GB][NC], s_u[GB][NC];
  __shared__ float s_prec[GB][NC], s_prec2[GB][NC];
  __shared__ float s_link[GB][NC][NC];
  __shared__ float s_rw[GB][NC], s_ww[GB][NC];
  __shared__ float s_rv[GB][CW];
  __shared__ float s_cw[GB][NC], s_cr[GB][NC], s_fwd[GB][NC], s_bwd[GB][NC];

  const int tid = threadIdx.x;
  const int bg  = blockIdx.x * GB;   // global batch base for this wg

  // ---- zero-init recurrent state ----
  for (int i = tid; i < GB*HID; i += BLK) { int b=i/HID, j=i%HID;
    s_h0[b][j]=0.f; s_c0[b][j]=0.f; s_h1[b][j]=0.f; s_c1[b][j]=0.f; s_ctrl[b][j]=0.f; }
  for (int i = tid; i < GB*NC*CW; i += BLK) { int b=i/(NC*CW), e=i%(NC*CW);
    s_mem[b][e/CW][e%CW]=0.f; }
  for (int i = tid; i < GB*NC*NC; i += BLK) { int b=i/(NC*NC), e=i%(NC*NC);
    s_link[b][e/NC][e%NC]=0.f; }
  if (tid < GB*NC) { int b=tid/NC, n=tid%NC;
    s_usage[b][n]=0.f; s_prec[b][n]=0.f; s_rw[b][n]=0.f; s_ww[b][n]=0.f; }
  if (tid < GB*CW) { int b=tid/CW, c=tid%CW; s_rv[b][c]=0.f; }
  __syncthreads();

  for (int t = 0; t < NT; ++t) {
    // ---- A: inp = concat(x_t, rv_prev) ----
    if (tid < GB*32) {
      int b = tid >> 5, i = tid & 31;
      float v = 0.f;
      if (i < NIN)      v = x[((size_t)(bg+b)*NT + t)*NIN + i];
      else if (i < NIN + CW) v = s_rv[b][i-NIN];
      s_inp[b][i] = v;
    }
    __syncthreads();

    // ---- B: gates0 = inp @ Wih0^T + h0_old @ Whh0^T + b0 ----
    {
      const int r = tid;
      float a0 = b0[r], a1 = a0;
      #pragma unroll
      for (int k = 0; k < NIN + CW; ++k) {
        float w = Wih0[r*(NIN+CW) + k];
        a0 += w * s_inp[0][k];
        a1 += w * s_inp[1][k];
      }
      const float4* Wr = reinterpret_cast<const float4*>(Whh0 + (size_t)r*HID);
      const float4* Ha = reinterpret_cast<const float4*>(s_h0[0]);
      const float4* Hb = reinterpret_cast<const float4*>(s_h0[1]);
      #pragma unroll 8
      for (int k = 0; k < HID/4; ++k) {
        float4 w = Wr[k], ha = Ha[k], hb = Hb[k];
        a0 += w.x*ha.x + w.y*ha.y + w.z*ha.z + w.w*ha.w;
        a1 += w.x*hb.x + w.y*hb.y + w.z*hb.z + w.w*hb.w;
      }
      s_g[0][r] = a0; s_g[1][r] = a1;
    }
    __syncthreads();

    // ---- C: LSTM0 nonlinearity ----
    if (tid < GB*HID) {
      int b = tid >> 7, j = tid & (HID-1);
      float gi=s_g[b][j], gf=s_g[b][HID+j], gg=s_g[b][2*HID+j], go=s_g[b][3*HID+j];
      float c = sigf(gf)*s_c0[b][j] + sigf(gi)*tanhf(gg);
      float h = sigf(go)*tanhf(c);
      s_c0[b][j]=c; s_h0[b][j]=h;
    }
    __syncthreads();

    // ---- D: gates1 = h0_new @ Wih1^T + h1_old @ Whh1^T + b1 ----
    {
      const int r = tid;
      float a0 = b1[r], a1 = a0;
      const float4* Wi = reinterpret_cast<const float4*>(Wih1 + (size_t)r*HID);
      const float4* Wh = reinterpret_cast<const float4*>(Whh1 + (size_t)r*HID);
      const float4* Xa = reinterpret_cast<const float4*>(s_h0[0]);
      const float4* Xb = reinterpret_cast<const float4*>(s_h0[1]);
      const float4* Ha = reinterpret_cast<const float4*>(s_h1[0]);
      const float4* Hb = reinterpret_cast<const float4*>(s_h1[1]);
      #pragma unroll 4
      for (int k = 0; k < HID/4; ++k) {
        float4 wi = Wi[k], wh = Wh[k];
        float4 xa = Xa[k], xb = Xb[k], ha = Ha[k], hb = Hb[k];
        a0 += wi.x*xa.x + wi.y*xa.y + wi.z*xa.z + wi.w*xa.w;
        a1 += wi.x*xb.x + wi.y*xb.y + wi.z*xb.z + wi.w*xb.w;
        a0 += wh.x*ha.x + wh.y*ha.y + wh.z*ha.z + wh.w*ha.w;
        a1 += wh.x*hb.x + wh.y*hb.y + wh.z*hb.z + wh.w*hb.w;
      }
      s_g[0][r] = a0; s_g[1][r] = a1;
    }
    __syncthreads();

    // ---- E: LSTM1 nonlinearity + ctrl clip ----
    if (tid < GB*HID) {
      int b = tid >> 7, j = tid & (HID-1);
      float gi=s_g[b][j], gf=s_g[b][HID+j], gg=s_g[b][2*HID+j], go=s_g[b][3*HID+j];
      float c = sigf(gf)*s_c1[b][j] + sigf(gi)*tanhf(gg);
      float h = sigf(go)*tanhf(c);
      s_c1[b][j]=c; s_h1[b][j]=h;
      s_ctrl[b][j] = fminf(fmaxf(h, -20.f), 20.f);
    }
    __syncthreads();

    // ---- F+G: xi = ctrl @ Wif^T + bif, fused with per-element transforms ----
    if (tid < GB*NIF) {
      int b = tid / NIF, q = tid - b*NIF;
      float a = bif[q];
      const float4* Wr = reinterpret_cast<const float4*>(Wif + (size_t)q*HID);
      const float4* C4 = reinterpret_cast<const float4*>(s_ctrl[b]);
      #pragma unroll 8
      for (int k = 0; k < HID/4; ++k) {
        float4 w = Wr[k], c = C4[k];
        a += w.x*c.x + w.y*c.y + w.z*c.z + w.w*c.w;
      }
      if      (q < 20)  s_rk[b][q]    = tanhf(a);
      else if (q == 20) s_sc[b][0]    = splus(a);   // rs
      else if (q < 41)  s_wk[b][q-21] = tanhf(a);
      else if (q == 41) s_sc[b][1]    = splus(a);   // ws
      else if (q < 62)  s_er[b][q-42] = sigf(a);
      else if (q < 82)  s_wv[b][q-62] = tanhf(a);
      else if (q == 82) s_sc[b][2]    = sigf(a);    // fg
      else if (q == 83) s_sc[b][3]    = sigf(a);    // ga
      else if (q == 84) s_sc[b][4]    = sigf(a);    // gw
      else              s_mraw[b][q-85] = a;        // modes raw
    }
    __syncthreads();

    // ---- H: usage update + write-content sims (+ modes softmax) ----
    if (tid < GB*NC) {
      int b = tid/NC, n = tid%NC;
      float fg  = s_sc[b][2];
      float psi = 1.f - fg * s_rw[b][n];           // R=1
      float u = s_usage[b][n], w = s_ww[b][n];     // OLD ww
      u = (u + w - u*w) * psi;
      s_usage[b][n] = u;
      s_u[b][n] = 1e-6f + (1.0f - 1e-6f) * u;
      float dot=0.f, mn=0.f, kn=0.f;               // content on OLD mem
      #pragma unroll
      for (int c = 0; c < CW; ++c) {
        float m = s_mem[b][n][c], k = s_wk[b][c];
        dot += k*m; mn += m*m; kn += k*k;
      }
      s_cw[b][n] = dot / (sqrtf(kn)*sqrtf(mn) + 1e-6f) * s_sc[b][1];
    } else if (tid >= 64 && tid < 64+GB) {
      int b = tid - 64;
      float m0=s_mraw[b][0], m1=s_mraw[b][1], m2=s_mraw[b][2];
      float mm = fmaxf(m0, fmaxf(m1, m2));
      float e0=expf(m0-mm), e1=expf(m1-mm), e2=expf(m2-mm);
      float es = e0+e1+e2;
      s_sc[b][5]=e0/es; s_sc[b][6]=e1/es; s_sc[b][7]=e2/es;
    }
    __syncthreads();

    // ---- I: cw softmax + rank-based allocation + new ww ----
    if (tid < GB*NC) {
      int b = tid/NC, n = tid%NC;
      float mx = -1e30f;
      #pragma unroll
      for (int m = 0; m < NC; ++m) mx = fmaxf(mx, s_cw[b][m]);
      float sm = 0.f;
      #pragma unroll
      for (int m = 0; m < NC; ++m) sm += expf(s_cw[b][m]-mx);
      float cw = expf(s_cw[b][n]-mx) / sm;
      // allocation: stable-rank exclusive product == stable argsort + cumprod
      float un = s_u[b][n];
      float excl = 1.f;
      #pragma unroll
      for (int m = 0; m < NC; ++m) {
        float um = s_u[b][m];
        bool before = (um < un) || (um == un && m < n);
        excl *= before ? um : 1.f;
      }
      float alloc = (1.f - un) * excl;
      float ga = s_sc[b][3], gw = s_sc[b][4];
      s_ww[b][n] = gw * (ga*alloc + (1.f-ga)*cw);
    }
    __syncthreads();

    // ---- J: memory write, link update (old prec), prec_new ----
    if (tid < GB*NC*CW) {
      int b = tid/(NC*CW), e = tid%(NC*CW), n = e/CW, c = e%CW;
      float w = s_ww[b][n];
      s_mem[b][n][c] = s_mem[b][n][c] * (1.f - w*s_er[b][c]) + w*s_wv[b][c];
    }
    if (tid < GB*NC*NC) {
      int b = tid/(NC*NC), e = tid%(NC*NC), i = e/NC, j = e%NC;
      float wi = s_ww[b][i], wj = s_ww[b][j];
      float l = (1.f - wi - wj)*s_link[b][i][j] + wi*s_prec[b][j];
      s_link[b][i][j] = (i==j) ? 0.f : l;
    }
    if (tid >= 480 && tid < 480+GB*NC) {
      int q = tid-480, b = q/NC, n = q%NC;
      float sw = 0.f;
      #pragma unroll
      for (int m = 0; m < NC; ++m) sw += s_ww[b][m];
      s_prec2[b][n] = (1.f - sw)*s_prec[b][n] + s_ww[b][n];
    }
    __syncthreads();

    // ---- K: commit prec, fwd/bwd (old rw, new link), read-content sims (new mem) ----
    if (tid < GB*NC) { int b=tid/NC, n=tid%NC; s_prec[b][n] = s_prec2[b][n]; }
    if (tid >= 64 && tid < 64 + GB*3*NC) {
      int q = tid-64, b = q/(3*NC), u = q%(3*NC);
      if (u < NC) {                       // fwd[m] = sum_n rw[n]*link[m][n]
        float a = 0.f;
        #pragma unroll
        for (int n = 0; n < NC; ++n) a += s_rw[b][n]*s_link[b][u][n];
        s_fwd[b][u] = a;
      } else if (u < 2*NC) {              // bwd[m] = sum_n rw[n]*link[n][m]
        int m = u-NC; float a = 0.f;
        #pragma unroll
        for (int n = 0; n < NC; ++n) a += s_rw[b][n]*s_link[b][n][m];
        s_bwd[b][m] = a;
      } else {                            // read content sim on NEW mem
        int n = u-2*NC;
        float dot=0.f, mn=0.f, kn=0.f;
        #pragma unroll
        for (int c = 0; c < CW; ++c) {
          float m = s_mem[b][n][c], k = s_rk[b][c];
          dot += k*m; mn += m*m; kn += k*k;
        }
        s_cr[b][n] = dot/(sqrtf(kn)*sqrtf(mn)+1e-6f) * s_sc[b][0];
      }
    }
    __syncthreads();

    // ---- L: cr softmax + new read weights ----
    if (tid < GB*NC) {
      int b = tid/NC, n = tid%NC;
      float mx = -1e30f;
      #pragma unroll
      for (int m = 0; m < NC; ++m) mx = fmaxf(mx, s_cr[b][m]);
      float sm = 0.f;
      #pragma unroll
      for (int m = 0; m < NC; ++m) sm += expf(s_cr[b][m]-mx);
      float cr = expf(s_cr[b][n]-mx)/sm;
      s_rw[b][n] = s_sc[b][5]*s_bwd[b][n] + s_sc[b][6]*cr + s_sc[b][7]*s_fwd[b][n];
    }
    __syncthreads();

    // ---- M: read vectors rv = rw @ mem ----
    if (tid < GB*CW) {
      int b = tid/CW, c = tid%CW;
      float a = 0.f;
      #pragma unroll
      for (int n = 0; n < NC; ++n) a += s_rw[b][n]*s_mem[b][n][c];
      s_rv[b][c] = a;
    }
    __syncthreads();
  }

  // ---- output: y_T = [ctrl, rv] @ Wout^T + bout ----
  if (tid < GB*NOUT) {
    int b = tid/NOUT, o = tid%NOUT;
    float a = bout[o];
    const float* Wr = Wout + o*(HID+CW);
    #pragma unroll 4
    for (int k = 0; k < HID; ++k) a += Wr[k]*s_ctrl[b][k];
    #pragma unroll
    for (int c = 0; c < CW; ++c) a += Wr[HID+c]*s_rv[b][c];
    out[(size_t)(bg+b)*NOUT + o] = a;
  }
}

extern "C" void kernel_launch(void* const* d_in, const int* in_sizes, int n_in,
                              void* d_out, int out_size, void* d_ws, size_t ws_size,
                              hipStream_t stream) {
  (void)in_sizes; (void)n_in; (void)out_size; (void)d_ws; (void)ws_size;
  const float* x    = (const float*)d_in[0];
  const float* Wih0 = (const float*)d_in[1];
  const float* Whh0 = (const float*)d_in[2];
  const float* b0   = (const float*)d_in[3];
  const float* Wih1 = (const float*)d_in[4];
  const float* Whh1 = (const float*)d_in[5];
  const float* b1   = (const float*)d_in[6];
  const float* Wif  = (const float*)d_in[7];
  const float* bif  = (const float*)d_in[8];
  const float* Wout = (const float*)d_in[9];
  const float* bout = (const float*)d_in[10];
  float* out = (float*)d_out;
  dnc_fp32_kernel<<<dim3(NB/GB), dim3(BLK), 0, stream>>>(
      x, Wih0, Whh0, b0, Wih1, Whh1, b1, Wif, bif, Wout, bout, out);
}